// Round 8
// baseline (322.867 us; speedup 1.0000x reference)
//
#include <hip/hip_runtime.h>
#include <cstdint>
#include <cstddef>

#define HB1 4096         // kC level-1 buckets (u>>19)
#define HB2 2048         // kC level-2 buckets ((u>>8)&0x7FF)
#define CMAX 21
#define IOU_T 0.5f

__device__ __forceinline__ float sl1(float x) {
    float ax = fabsf(x);
    return ax < 1.0f ? 0.5f * x * x : ax - 0.5f;
}

// ---------------- Kernel A: per-truth argmax over prior slices (+ zero-init fold) ----------------
__global__ __launch_bounds__(256) void kA_best_prior(
    const float* __restrict__ targets, const float* __restrict__ priors,
    float* __restrict__ bpi_val, int* __restrict__ bpi_idx,
    int* __restrict__ num_pos_g, float* __restrict__ accB_g,
    float* __restrict__ acc_g, unsigned* __restrict__ done_g,
    int N, int NOBJ, int SLICES, int CHUNK, int B)
{
    const int s = blockIdx.x, b = blockIdx.y, t = threadIdx.x;
    __shared__ float tb[16 * 4];
    __shared__ float ta[16];
    __shared__ float wv[4 * 16];
    __shared__ int   wi[4 * 16];

    if (s == 0 && b == 0) {
        for (int q = t; q < B; q += 256) num_pos_g[q] = 0;
        for (int q = t; q < 2 * B; q += 256) accB_g[q] = 0.f;
        if (t < 4) acc_g[t] = 0.f;
        if (t == 0) *done_g = 0u;
    }

    if (t < 16) {
        if (t < NOBJ) {
            const float* tr = targets + ((size_t)b * NOBJ + t) * 5;
            float x0 = tr[0], y0 = tr[1], x1 = tr[2], y1 = tr[3];
            tb[t * 4 + 0] = x0; tb[t * 4 + 1] = y0;
            tb[t * 4 + 2] = x1; tb[t * 4 + 3] = y1;
            ta[t] = (x1 - x0) * (y1 - y0);
        } else {
            tb[t * 4 + 0] = 0.f; tb[t * 4 + 1] = 0.f;
            tb[t * 4 + 2] = 0.f; tb[t * 4 + 3] = 0.f;
            ta[t] = 0.f;
        }
    }
    __syncthreads();

    float bv[16]; int bi[16];
#pragma unroll
    for (int j = 0; j < 16; j++) { bv[j] = -1.0f; bi[j] = 0x7fffffff; }

    const int start = s * CHUNK;
    const int end = min(start + CHUNK, N);
    for (int i = start + t; i < end; i += 256) {
        float4 p = ((const float4*)priors)[i];
        float bx0 = p.x - p.z * 0.5f, by0 = p.y - p.w * 0.5f;
        float bx1 = p.x + p.z * 0.5f, by1 = p.y + p.w * 0.5f;
        float ab = (bx1 - bx0) * (by1 - by0);
#pragma unroll
        for (int j = 0; j < 16; j++) {
            float iw = fminf(tb[j * 4 + 2], bx1) - fmaxf(tb[j * 4 + 0], bx0);
            float ih = fminf(tb[j * 4 + 3], by1) - fmaxf(tb[j * 4 + 1], by0);
            iw = fmaxf(iw, 0.f); ih = fmaxf(ih, 0.f);
            float inter = iw * ih;
            float iou = inter / (ta[j] + ab - inter);
            if (iou > bv[j] || (iou == bv[j] && i < bi[j])) { bv[j] = iou; bi[j] = i; }
        }
    }

#pragma unroll
    for (int off = 32; off >= 1; off >>= 1) {
#pragma unroll
        for (int j = 0; j < 16; j++) {
            float v2 = __shfl_down(bv[j], off, 64);
            int   i2 = __shfl_down(bi[j], off, 64);
            if (v2 > bv[j] || (v2 == bv[j] && i2 < bi[j])) { bv[j] = v2; bi[j] = i2; }
        }
    }
    const int wid = t >> 6, lane = t & 63;
    if (lane == 0) {
#pragma unroll
        for (int j = 0; j < 16; j++) { wv[wid * 16 + j] = bv[j]; wi[wid * 16 + j] = bi[j]; }
    }
    __syncthreads();
    if (t < 16) {
        float v = wv[t]; int idx = wi[t];
#pragma unroll
        for (int w = 1; w < 4; w++) {
            float v2 = wv[w * 16 + t]; int i2 = wi[w * 16 + t];
            if (v2 > v || (v2 == v && i2 < idx)) { v = v2; idx = i2; }
        }
        if (t < NOBJ) {
            int o = (b * SLICES + s) * 16 + t;
            bpi_val[o] = v;
            bpi_idx[o] = idx;
        }
    }
}

// ---------------- Kernel B: wave-private pipelined tiles — zero loop barriers ----------------
#define IOU_STEP(j) { \
    float4 tj = tb4[j]; \
    float taj = (tj.z - tj.x) * (tj.w - tj.y); \
    float iw = fminf(tj.z, bx1) - fmaxf(tj.x, bx0); \
    float ih = fminf(tj.w, by1) - fmaxf(tj.y, by0); \
    iw = fmaxf(iw, 0.f); ih = fmaxf(ih, 0.f); \
    float inter = iw * ih; \
    float iou = inter * __builtin_amdgcn_rcpf(taj + ab - inter); \
    if (iou > bto) { bto = iou; bti = (j); } }

__global__ __launch_bounds__(256, 6) void kB_main(
    const float* __restrict__ loc, const float* __restrict__ conf,
    const float* __restrict__ targets, const float* __restrict__ priors,
    const float* __restrict__ bpi_val, const int* __restrict__ bpi_idx,
    float* __restrict__ lc_out, int* __restrict__ num_pos, float* __restrict__ accB,
    int N, int NOBJ, int SLICES, int TPB, int BPB)
{
    const int g = blockIdx.x;
    const int b = g / BPB;
    const int j0 = g % BPB;
    const int t = threadIdx.x;
    const int wid = t >> 6, lane = t & 63;

    __shared__ __align__(16) float buf[4][64 * CMAX];   // per-wave private slices, 5376 B each
    __shared__ __align__(16) float tb[16 * 4];
    __shared__ float tl[16];
    __shared__ __align__(16) int bpi_s[16];
    __shared__ float wred[4 * 3];

    if (t < 16) {
        if (t < NOBJ) {
            const float* tr = targets + ((size_t)b * NOBJ + t) * 5;
            tb[t * 4 + 0] = tr[0]; tb[t * 4 + 1] = tr[1];
            tb[t * 4 + 2] = tr[2]; tb[t * 4 + 3] = tr[3];
            tl[t] = tr[4];
            float bv = -1.f; int bi = 0x7fffffff;
            for (int s2 = 0; s2 < SLICES; s2++) {
                int o = (b * SLICES + s2) * 16 + t;
                float v = bpi_val[o]; int idx = bpi_idx[o];
                if (v > bv || (v == bv && idx < bi)) { bv = v; bi = idx; }
            }
            bpi_s[t] = bi;
        } else {
            tb[t * 4 + 0] = 0.f; tb[t * 4 + 1] = 0.f; tb[t * 4 + 2] = 0.f; tb[t * 4 + 3] = 0.f;
            tl[t] = 0.f; bpi_s[t] = -1;
        }
    }
    __syncthreads();   // the ONLY pre-loop barrier: tb/tl/bpi_s ready

    const float* confB = conf + (size_t)b * N * CMAX;
    const float* locB  = loc + (size_t)b * N * 4;
    float* myLDS = buf[wid];

    float4 r0 = {}, r1 = {}, r2 = {}, r3 = {}, r4 = {}, r5 = {};
    float4 pld = {}, ppr = {};

    // stage this wave's 64-row micro-tile of tile xx into registers (coalesced float4s)
    auto stage = [&](int xx) {
        int row0 = xx * 256 + wid * 64;
        if (row0 >= N) return;
        int rows_s = min(64, N - row0);
        int nf4s = (rows_s * CMAX) >> 2;
        const float4* s4 = (const float4*)(confB + (size_t)row0 * CMAX);
        if (lane + 0   < nf4s) r0 = s4[lane + 0];
        if (lane + 64  < nf4s) r1 = s4[lane + 64];
        if (lane + 128 < nf4s) r2 = s4[lane + 128];
        if (lane + 192 < nf4s) r3 = s4[lane + 192];
        if (lane + 256 < nf4s) r4 = s4[lane + 256];
        if (lane + 320 < nf4s) r5 = s4[lane + 320];
        if (lane < rows_s) {
            ppr = ((const float4*)priors)[row0 + lane];
            pld = ((const float4*)locB)[row0 + lane];
        }
    };

    float ll = 0.f, plc = 0.f, np = 0.f;
    int x = j0;
    stage(x);

    while (x < TPB) {
        const int row0 = x * 256 + wid * 64;
        const int rows = (row0 < N) ? min(64, N - row0) : 0;
        const int nf4 = (rows * CMAX) >> 2;

        float4 myp = ppr, myl = pld;   // snapshot before restage

        // drain staged regs into this wave's private LDS slice (wave-local ordering)
        float4* d4 = (float4*)myLDS;
        if (lane + 0   < nf4) d4[lane + 0]   = r0;
        if (lane + 64  < nf4) d4[lane + 64]  = r1;
        if (lane + 128 < nf4) d4[lane + 128] = r2;
        if (lane + 192 < nf4) d4[lane + 192] = r3;
        if (lane + 256 < nf4) d4[lane + 256] = r4;
        if (lane + 320 < nf4) d4[lane + 320] = r5;
        {   // scalar tail (rows*21 not multiple of 4)
            int nf = rows * CMAX;
            int rem = nf - (nf4 << 2);
            if (lane < rem) myLDS[(nf4 << 2) + lane] = confB[(size_t)row0 * CMAX + (nf4 << 2) + lane];
        }

        int xn = x + BPB;
        if (xn < TPB) stage(xn);   // issue next tile's loads; latency covered by compute below

        if (lane < rows) {
            const int i = row0 + lane;
            float4 pp = myp;
            float bx0 = pp.x - pp.z * 0.5f, by0 = pp.y - pp.w * 0.5f;
            float bx1 = pp.x + pp.z * 0.5f, by1 = pp.y + pp.w * 0.5f;
            float ab = (bx1 - bx0) * (by1 - by0);
            float bto = -1.f; int bti = 0;
            const float4* tb4 = (const float4*)tb;
            if (NOBJ == 16) {
#pragma unroll
                for (int j = 0; j < 16; j++) IOU_STEP(j);
            } else {
                for (int j = 0; j < NOBJ; j++) IOU_STEP(j);
            }
            const int4* bp4 = (const int4*)bpi_s;
#pragma unroll
            for (int jj = 0; jj < 4; jj++) {          // override, last j wins
                int4 q = bp4[jj];
                if (q.x == i) { bto = 2.0f; bti = jj * 4 + 0; }
                if (q.y == i) { bto = 2.0f; bti = jj * 4 + 1; }
                if (q.z == i) { bto = 2.0f; bti = jj * 4 + 2; }
                if (q.w == i) { bto = 2.0f; bti = jj * 4 + 3; }
            }
            bool pos = !(bto < IOU_T);
            if (pos) {
                float4 tj = tb4[bti];
                float rz = __builtin_amdgcn_rcpf(pp.z);
                float rw = __builtin_amdgcn_rcpf(pp.w);
                float gcx = ((tj.x + tj.z) * 0.5f - pp.x) * (10.0f * rz);
                float gcy = ((tj.y + tj.w) * 0.5f - pp.y) * (10.0f * rw);
                float gw = __logf((tj.z - tj.x) * rz) * 5.0f;
                float gh = __logf((tj.w - tj.y) * rw) * 5.0f;
                ll += sl1(myl.x - gcx) + sl1(myl.y - gcy) + sl1(myl.z - gw) + sl1(myl.w - gh);
                np += 1.f;
            }
            int cf = pos ? ((int)tl[bti] + 1) : 0;
            const float* cr = myLDS + lane * CMAX;
            float m = cr[0];
#pragma unroll
            for (int c = 1; c < CMAX; c++) m = fmaxf(m, cr[c]);
            float ssum = 0.f;
#pragma unroll
            for (int c = 0; c < CMAX; c++) ssum += __expf(cr[c] - m);
            float lse = m + __logf(ssum);
            float lossc = lse - cr[cf];
            if (pos) plc += lossc;
            float lcv = pos ? 0.f : lossc;
            lcv = fmaxf(lcv, 0.f);
            lc_out[(size_t)b * N + i] = lcv;
        }
        x = xn;
    }

    // block reduction, 3 atomics per block
#pragma unroll
    for (int off = 32; off >= 1; off >>= 1) {
        ll  += __shfl_down(ll, off, 64);
        plc += __shfl_down(plc, off, 64);
        np  += __shfl_down(np, off, 64);
    }
    if (lane == 0) { wred[wid * 3 + 0] = ll; wred[wid * 3 + 1] = plc; wred[wid * 3 + 2] = np; }
    __syncthreads();
    if (t == 0) {
        float a0 = 0.f, a1 = 0.f, a2 = 0.f;
#pragma unroll
        for (int w = 0; w < 4; w++) { a0 += wred[w * 3 + 0]; a1 += wred[w * 3 + 1]; a2 += wred[w * 3 + 2]; }
        atomicAdd(&accB[b * 2 + 0], a0);
        atomicAdd(&accB[b * 2 + 1], a1);
        atomicAdd(&num_pos[b], (int)a2);
    }
}

// ---------------- Kernel C: 2-level radix select, hierarchical shuffle suffix-scan ----------------
__device__ __forceinline__ void wave_sufscan(int& c, float& s, int lane) {
#pragma unroll
    for (int off = 1; off < 64; off <<= 1) {
        int c2 = __shfl_down(c, off, 64);
        float s2 = __shfl_down(s, off, 64);
        if (lane + off < 64) { c += c2; s += s2; }
    }
}

__global__ __launch_bounds__(1024) void kC_topk(
    const float* __restrict__ lc, const int* __restrict__ num_pos,
    const float* __restrict__ accB,
    float* __restrict__ acc, unsigned* __restrict__ done_ctr,
    float* __restrict__ out, int N, int B)
{
    const int b = blockIdx.x, t = threadIdx.x;
    const int NT = 1024;
    const int wid = t >> 6, lane = t & 63;   // 16 waves
    __shared__ __align__(16) int   cnt[HB1];
    __shared__ __align__(16) float sm[HB1];
    __shared__ int   wc[16];
    __shared__ float ws[16];
    __shared__ int s_strad, s_krem;
    __shared__ float s_above;
    __shared__ int s_last;
    __shared__ float wsum[16], wsA[16], wsB[16];

    const int k = min(3 * num_pos[b], N - 1);
    const float* lcb = lc + (size_t)b * N;
    float total = 0.f;

    if (k > 0) {
        // ---- Level 1: bits [30:19] (4096 buckets), thread owns 4 ----
        ((int4*)cnt)[t] = make_int4(0, 0, 0, 0);
        ((float4*)sm)[t] = make_float4(0.f, 0.f, 0.f, 0.f);
        __syncthreads();
        const int n4 = N >> 2;
        const float4* lcb4 = (const float4*)lcb;
        for (int i = t; i < n4; i += NT) {
            float4 v = lcb4[i];
            { unsigned u = __float_as_uint(v.x) >> 19; atomicAdd(&cnt[u], 1); atomicAdd(&sm[u], v.x); }
            { unsigned u = __float_as_uint(v.y) >> 19; atomicAdd(&cnt[u], 1); atomicAdd(&sm[u], v.y); }
            { unsigned u = __float_as_uint(v.z) >> 19; atomicAdd(&cnt[u], 1); atomicAdd(&sm[u], v.z); }
            { unsigned u = __float_as_uint(v.w) >> 19; atomicAdd(&cnt[u], 1); atomicAdd(&sm[u], v.w); }
        }
        for (int i = (n4 << 2) + t; i < N; i += NT) {
            float v = lcb[i];
            unsigned u = __float_as_uint(v) >> 19;
            atomicAdd(&cnt[u], 1); atomicAdd(&sm[u], v);
        }
        __syncthreads();
        {
            int4  cv = ((const int4*)cnt)[t];
            float4 sv = ((const float4*)sm)[t];
            int   ci = cv.x + cv.y + cv.z + cv.w;
            float si = sv.x + sv.y + sv.z + sv.w;
            wave_sufscan(ci, si, lane);
            if (lane == 0) { wc[wid] = ci; ws[wid] = si; }
            __syncthreads();
            int cab = 0; float sab = 0.f;
            for (int w = wid + 1; w < 16; w++) { cab += wc[w]; sab += ws[w]; }
            int   i0c = ci + cab;          float f0 = si + sab;
            int   i1c = i0c - cv.x;        float f1 = f0 - sv.x;
            int   i2c = i1c - cv.y;        float f2 = f1 - sv.y;
            int   i3c = i2c - cv.z;        float f3 = f2 - sv.z;
            int   i4c = i3c - cv.w;
            if (i1c < k && k <= i0c) { s_strad = 4 * t + 0; s_krem = k - i1c; s_above = f1; }
            if (i2c < k && k <= i1c) { s_strad = 4 * t + 1; s_krem = k - i2c; s_above = f2; }
            if (i3c < k && k <= i2c) { s_strad = 4 * t + 2; s_krem = k - i3c; s_above = f3; }
            if (i4c < k && k <= i3c) { s_strad = 4 * t + 3; s_krem = k - i4c; s_above = f3 - sv.w; }
        }
        __syncthreads();
        const int s1 = s_strad, k2 = s_krem;
        total += s_above;

        // ---- Level 2: bits [18:8] (2048 buckets) within L1 bucket s1, thread owns 2 ----
        __syncthreads();
        ((int2*)cnt)[t] = make_int2(0, 0);
        ((float2*)sm)[t] = make_float2(0.f, 0.f);
        __syncthreads();
        for (int i = t; i < N; i += NT) {
            float v = lcb[i];
            unsigned u = __float_as_uint(v);
            if ((int)(u >> 19) == s1) {
                int q = (int)((u >> 8) & 0x7FF);
                atomicAdd(&cnt[q], 1); atomicAdd(&sm[q], v);
            }
        }
        __syncthreads();
        {
            int2  cv = ((const int2*)cnt)[t];
            float2 sv = ((const float2*)sm)[t];
            int   ci = cv.x + cv.y;
            float si = sv.x + sv.y;
            wave_sufscan(ci, si, lane);
            if (lane == 0) { wc[wid] = ci; ws[wid] = si; }
            __syncthreads();
            int cab = 0; float sab = 0.f;
            for (int w = wid + 1; w < 16; w++) { cab += wc[w]; sab += ws[w]; }
            int   i0c = ci + cab;       float f0 = si + sab;
            int   i1c = i0c - cv.x;     float f1 = f0 - sv.x;
            int   i2c = i1c - cv.y;
            if (i1c < k2 && k2 <= i0c) { s_strad = 2 * t + 0; s_krem = k2 - i1c; s_above = f1; }
            if (i2c < k2 && k2 <= i1c) { s_strad = 2 * t + 1; s_krem = k2 - i2c; s_above = f1 - sv.y; }
        }
        __syncthreads();
        const int s2 = s_strad, krem = s_krem;
        total += s_above;
        float tval = __uint_as_float((((unsigned)s1) << 19) | (((unsigned)s2) << 8));
        total += (float)krem * tval;
    }

    // contribute + last-block finalize
    if (t == 0) {
        if (k > 0) atomicAdd(&acc[1], total);
        __threadfence();
        unsigned old = atomicAdd(done_ctr, 1u);
        s_last = (old == (unsigned)gridDim.x - 1u) ? 1 : 0;
    }
    __syncthreads();
    if (s_last) {
        __threadfence();
        float vn = 0.f, va = 0.f, vb = 0.f;
        for (int q = t; q < B; q += NT) {
            vn += (float)num_pos[q];
            va += accB[q * 2 + 0];
            vb += accB[q * 2 + 1];
        }
#pragma unroll
        for (int off = 32; off >= 1; off >>= 1) {
            vn += __shfl_down(vn, off, 64);
            va += __shfl_down(va, off, 64);
            vb += __shfl_down(vb, off, 64);
        }
        if (lane == 0) { wsum[wid] = vn; wsA[wid] = va; wsB[wid] = vb; }
        __syncthreads();
        if (t == 0) {
            float n = 0.f, a = 0.f, bsum = 0.f;
#pragma unroll
            for (int w = 0; w < 16; w++) { n += wsum[w]; a += wsA[w]; bsum += wsB[w]; }
            float l2 = atomicAdd(&acc[1], 0.0f);
            out[0] = a / n;
            out[1] = (bsum + l2) / n;
        }
    }
}

extern "C" void kernel_launch(void* const* d_in, const int* in_sizes, int n_in,
                              void* d_out, int out_size, void* d_ws, size_t ws_size,
                              hipStream_t stream)
{
    const float* loc     = (const float*)d_in[0];
    const float* conf    = (const float*)d_in[1];
    const float* targets = (const float*)d_in[2];
    const float* priors  = (const float*)d_in[3];
    float* out = (float*)d_out;

    const int N = in_sizes[3] / 4;
    const int BN = in_sizes[0] / 4;
    const int B = BN / N;
    const int NOBJ = in_sizes[2] / (B * 5);
    const int SLICES = 8;
    const int CHUNK = (N + SLICES - 1) / SLICES;
    const int TPB = (N + 255) / 256;     // 256-row macro-tiles per batch
    const int BPB = 8;                   // blocks per batch -> 1024 blocks = 4/CU

    // workspace layout
    char* w = (char*)d_ws;
    float*    lc_ws   = (float*)w;                         size_t off = (size_t)BN * 4;
    float*    bpi_val = (float*)(w + off);                 off += (size_t)B * SLICES * 16 * 4;
    int*      bpi_idx = (int*)(w + off);                   off += (size_t)B * SLICES * 16 * 4;
    int*      num_pos = (int*)(w + off);                   off += (size_t)B * 4;
    float*    accB    = (float*)(w + off);                 off += (size_t)B * 2 * 4;
    float*    acc     = (float*)(w + off);                 off += 16;
    unsigned* done    = (unsigned*)(w + off);              off += 16;

    dim3 gA(SLICES, B);
    kA_best_prior<<<gA, 256, 0, stream>>>(targets, priors, bpi_val, bpi_idx,
                                          num_pos, accB, acc, done, N, NOBJ, SLICES, CHUNK, B);

    kB_main<<<B * BPB, 256, 0, stream>>>(loc, conf, targets, priors, bpi_val, bpi_idx,
                                         lc_ws, num_pos, accB, N, NOBJ, SLICES, TPB, BPB);

    kC_topk<<<B, 1024, 0, stream>>>(lc_ws, num_pos, accB, acc, done, out, N, B);
}

// Round 9
// 225.602 us; speedup vs baseline: 1.4311x; 1.4311x over previous
//
#include <hip/hip_runtime.h>
#include <cstdint>
#include <cstddef>

#define HB1 4096         // kC level-1 buckets (u>>19)
#define HB2 2048         // kC level-2 buckets ((u>>8)&0x7FF)
#define CMAX 21
#define IOU_T 0.5f

__device__ __forceinline__ float sl1(float x) {
    float ax = fabsf(x);
    return ax < 1.0f ? 0.5f * x * x : ax - 0.5f;
}

// ---------------- Kernel A: per-truth argmax over prior slices (+ zero-init fold) ----------------
__global__ __launch_bounds__(256) void kA_best_prior(
    const float* __restrict__ targets, const float* __restrict__ priors,
    float* __restrict__ bpi_val, int* __restrict__ bpi_idx,
    int* __restrict__ num_pos_g, float* __restrict__ accB_g,
    float* __restrict__ acc_g, unsigned* __restrict__ done_g,
    int N, int NOBJ, int SLICES, int CHUNK, int B)
{
    const int s = blockIdx.x, b = blockIdx.y, t = threadIdx.x;
    __shared__ float tb[16 * 4];
    __shared__ float ta[16];
    __shared__ float wv[4 * 16];
    __shared__ int   wi[4 * 16];

    if (s == 0 && b == 0) {
        for (int q = t; q < B; q += 256) num_pos_g[q] = 0;
        for (int q = t; q < 2 * B; q += 256) accB_g[q] = 0.f;
        if (t < 4) acc_g[t] = 0.f;
        if (t == 0) *done_g = 0u;
    }

    if (t < 16) {
        if (t < NOBJ) {
            const float* tr = targets + ((size_t)b * NOBJ + t) * 5;
            float x0 = tr[0], y0 = tr[1], x1 = tr[2], y1 = tr[3];
            tb[t * 4 + 0] = x0; tb[t * 4 + 1] = y0;
            tb[t * 4 + 2] = x1; tb[t * 4 + 3] = y1;
            ta[t] = (x1 - x0) * (y1 - y0);
        } else {
            tb[t * 4 + 0] = 0.f; tb[t * 4 + 1] = 0.f;
            tb[t * 4 + 2] = 0.f; tb[t * 4 + 3] = 0.f;
            ta[t] = 0.f;
        }
    }
    __syncthreads();

    float bv[16]; int bi[16];
#pragma unroll
    for (int j = 0; j < 16; j++) { bv[j] = -1.0f; bi[j] = 0x7fffffff; }

    const int start = s * CHUNK;
    const int end = min(start + CHUNK, N);
    for (int i = start + t; i < end; i += 256) {
        float4 p = ((const float4*)priors)[i];
        float bx0 = p.x - p.z * 0.5f, by0 = p.y - p.w * 0.5f;
        float bx1 = p.x + p.z * 0.5f, by1 = p.y + p.w * 0.5f;
        float ab = (bx1 - bx0) * (by1 - by0);
#pragma unroll
        for (int j = 0; j < 16; j++) {
            float iw = fminf(tb[j * 4 + 2], bx1) - fmaxf(tb[j * 4 + 0], bx0);
            float ih = fminf(tb[j * 4 + 3], by1) - fmaxf(tb[j * 4 + 1], by0);
            iw = fmaxf(iw, 0.f); ih = fmaxf(ih, 0.f);
            float inter = iw * ih;
            float iou = inter / (ta[j] + ab - inter);
            if (iou > bv[j] || (iou == bv[j] && i < bi[j])) { bv[j] = iou; bi[j] = i; }
        }
    }

#pragma unroll
    for (int off = 32; off >= 1; off >>= 1) {
#pragma unroll
        for (int j = 0; j < 16; j++) {
            float v2 = __shfl_down(bv[j], off, 64);
            int   i2 = __shfl_down(bi[j], off, 64);
            if (v2 > bv[j] || (v2 == bv[j] && i2 < bi[j])) { bv[j] = v2; bi[j] = i2; }
        }
    }
    const int wid = t >> 6, lane = t & 63;
    if (lane == 0) {
#pragma unroll
        for (int j = 0; j < 16; j++) { wv[wid * 16 + j] = bv[j]; wi[wid * 16 + j] = bi[j]; }
    }
    __syncthreads();
    if (t < 16) {
        float v = wv[t]; int idx = wi[t];
#pragma unroll
        for (int w = 1; w < 4; w++) {
            float v2 = wv[w * 16 + t]; int i2 = wi[w * 16 + t];
            if (v2 > v || (v2 == v && i2 < idx)) { v = v2; idx = i2; }
        }
        if (t < NOBJ) {
            int o = (b * SLICES + s) * 16 + t;
            bpi_val[o] = v;
            bpi_idx[o] = idx;
        }
    }
}

// ---------------- Kernel B: software-pipelined multi-tile (reg-staged double-buffered LDS) ----------------
// R7-proven version: straight-line guarded staging (no lambda-local control flow that
// could demote staging regs to scratch), one barrier per tile, BPB=6 -> 3 blocks/CU.
#define IOU_STEP(j) { \
    float4 tj = tb4[j]; \
    float taj = (tj.z - tj.x) * (tj.w - tj.y); \
    float iw = fminf(tj.z, bx1) - fmaxf(tj.x, bx0); \
    float ih = fminf(tj.w, by1) - fmaxf(tj.y, by0); \
    iw = fmaxf(iw, 0.f); ih = fmaxf(ih, 0.f); \
    float inter = iw * ih; \
    float iou = inter * __builtin_amdgcn_rcpf(taj + ab - inter); \
    if (iou > bto) { bto = iou; bti = (j); } }

__global__ __launch_bounds__(256, 3) void kB_main(
    const float* __restrict__ loc, const float* __restrict__ conf,
    const float* __restrict__ targets, const float* __restrict__ priors,
    const float* __restrict__ bpi_val, const int* __restrict__ bpi_idx,
    float* __restrict__ lc_out, int* __restrict__ num_pos, float* __restrict__ accB,
    int N, int NOBJ, int SLICES, int TPB, int BPB)
{
    const int g = blockIdx.x;
    const int b = g / BPB;
    const int j0 = g % BPB;
    const int t = threadIdx.x;
    const int wid = t >> 6, lane = t & 63;

    __shared__ __align__(16) float buf[2][256 * CMAX];   // 2 x 21504 B
    __shared__ __align__(16) float tb[16 * 4];
    __shared__ float tl[16];
    __shared__ __align__(16) int bpi_s[16];
    __shared__ float wred[4 * 3];

    if (t < 16) {
        if (t < NOBJ) {
            const float* tr = targets + ((size_t)b * NOBJ + t) * 5;
            tb[t * 4 + 0] = tr[0]; tb[t * 4 + 1] = tr[1];
            tb[t * 4 + 2] = tr[2]; tb[t * 4 + 3] = tr[3];
            tl[t] = tr[4];
            float bv = -1.f; int bi = 0x7fffffff;
            for (int s2 = 0; s2 < SLICES; s2++) {
                int o = (b * SLICES + s2) * 16 + t;
                float v = bpi_val[o]; int idx = bpi_idx[o];
                if (v > bv || (v == bv && idx < bi)) { bv = v; bi = idx; }
            }
            bpi_s[t] = bi;
        } else {
            tb[t * 4 + 0] = 0.f; tb[t * 4 + 1] = 0.f; tb[t * 4 + 2] = 0.f; tb[t * 4 + 3] = 0.f;
            tl[t] = 0.f; bpi_s[t] = -1;
        }
    }

    const float* confB = conf + (size_t)b * N * CMAX;
    const float* locB  = loc + (size_t)b * N * 4;

    float4 r0, r1, r2, r3, r4, r5, pld, ppr;

    auto stage = [&](int xx) {
        int i0s = xx * 256;
        int rows_s = min(256, N - i0s);
        int nf4s = (rows_s * CMAX) >> 2;
        const float4* s4 = (const float4*)(confB + (size_t)i0s * CMAX);
        if (t + 0    < nf4s) r0 = s4[t + 0];
        if (t + 256  < nf4s) r1 = s4[t + 256];
        if (t + 512  < nf4s) r2 = s4[t + 512];
        if (t + 768  < nf4s) r3 = s4[t + 768];
        if (t + 1024 < nf4s) r4 = s4[t + 1024];
        if (t + 1280 < nf4s) r5 = s4[t + 1280];
        if (t < rows_s) {
            ppr = ((const float4*)priors)[i0s + t];
            pld = ((const float4*)locB)[i0s + t];
        }
    };

    float ll = 0.f, plc = 0.f, np = 0.f;
    int x = j0, p = 0;
    if (x < TPB) stage(x);

    while (x < TPB) {
        const int i0 = x * 256;
        const int rows = min(256, N - i0);
        const int nf4 = (rows * CMAX) >> 2;

        float4 myp = ppr, myl = pld;

        float4* bp4f = (float4*)buf[p];
        if (t + 0    < nf4) bp4f[t + 0]    = r0;
        if (t + 256  < nf4) bp4f[t + 256]  = r1;
        if (t + 512  < nf4) bp4f[t + 512]  = r2;
        if (t + 768  < nf4) bp4f[t + 768]  = r3;
        if (t + 1024 < nf4) bp4f[t + 1024] = r4;
        if (t + 1280 < nf4) bp4f[t + 1280] = r5;
        __syncthreads();

        int xn = x + BPB;
        if (xn < TPB) stage(xn);

        if (t < rows) {
            const int i = i0 + t;
            float4 pp = myp;
            float bx0 = pp.x - pp.z * 0.5f, by0 = pp.y - pp.w * 0.5f;
            float bx1 = pp.x + pp.z * 0.5f, by1 = pp.y + pp.w * 0.5f;
            float ab = (bx1 - bx0) * (by1 - by0);
            float bto = -1.f; int bti = 0;
            const float4* tb4 = (const float4*)tb;
            if (NOBJ == 16) {
#pragma unroll
                for (int j = 0; j < 16; j++) IOU_STEP(j);
            } else {
                for (int j = 0; j < NOBJ; j++) IOU_STEP(j);
            }
            const int4* bp4 = (const int4*)bpi_s;
#pragma unroll
            for (int jj = 0; jj < 4; jj++) {
                int4 q = bp4[jj];
                if (q.x == i) { bto = 2.0f; bti = jj * 4 + 0; }
                if (q.y == i) { bto = 2.0f; bti = jj * 4 + 1; }
                if (q.z == i) { bto = 2.0f; bti = jj * 4 + 2; }
                if (q.w == i) { bto = 2.0f; bti = jj * 4 + 3; }
            }
            bool pos = !(bto < IOU_T);
            if (pos) {
                float4 tj = tb4[bti];
                float rz = __builtin_amdgcn_rcpf(pp.z);
                float rw = __builtin_amdgcn_rcpf(pp.w);
                float gcx = ((tj.x + tj.z) * 0.5f - pp.x) * (10.0f * rz);
                float gcy = ((tj.y + tj.w) * 0.5f - pp.y) * (10.0f * rw);
                float gw = __logf((tj.z - tj.x) * rz) * 5.0f;
                float gh = __logf((tj.w - tj.y) * rw) * 5.0f;
                ll += sl1(myl.x - gcx) + sl1(myl.y - gcy) + sl1(myl.z - gw) + sl1(myl.w - gh);
                np += 1.f;
            }
            int cf = pos ? ((int)tl[bti] + 1) : 0;
            const float* cr = buf[p] + t * CMAX;
            float m = cr[0];
#pragma unroll
            for (int c = 1; c < CMAX; c++) m = fmaxf(m, cr[c]);
            float ssum = 0.f;
#pragma unroll
            for (int c = 0; c < CMAX; c++) ssum += __expf(cr[c] - m);
            float lse = m + __logf(ssum);
            float lossc = lse - cr[cf];
            if (pos) plc += lossc;
            float lcv = pos ? 0.f : lossc;
            lcv = fmaxf(lcv, 0.f);
            lc_out[(size_t)b * N + i] = lcv;
        }
        p ^= 1;
        x = xn;
    }

#pragma unroll
    for (int off = 32; off >= 1; off >>= 1) {
        ll  += __shfl_down(ll, off, 64);
        plc += __shfl_down(plc, off, 64);
        np  += __shfl_down(np, off, 64);
    }
    if (lane == 0) { wred[wid * 3 + 0] = ll; wred[wid * 3 + 1] = plc; wred[wid * 3 + 2] = np; }
    __syncthreads();
    if (t == 0) {
        float a0 = 0.f, a1 = 0.f, a2 = 0.f;
#pragma unroll
        for (int w = 0; w < 4; w++) { a0 += wred[w * 3 + 0]; a1 += wred[w * 3 + 1]; a2 += wred[w * 3 + 2]; }
        atomicAdd(&accB[b * 2 + 0], a0);
        atomicAdd(&accB[b * 2 + 1], a1);
        atomicAdd(&num_pos[b], (int)a2);
    }
}

// ---------------- Kernel C: 2-level radix select, hierarchical shuffle suffix-scan ----------------
__device__ __forceinline__ void wave_sufscan(int& c, float& s, int lane) {
#pragma unroll
    for (int off = 1; off < 64; off <<= 1) {
        int c2 = __shfl_down(c, off, 64);
        float s2 = __shfl_down(s, off, 64);
        if (lane + off < 64) { c += c2; s += s2; }
    }
}

__global__ __launch_bounds__(1024) void kC_topk(
    const float* __restrict__ lc, const int* __restrict__ num_pos,
    const float* __restrict__ accB,
    float* __restrict__ acc, unsigned* __restrict__ done_ctr,
    float* __restrict__ out, int N, int B)
{
    const int b = blockIdx.x, t = threadIdx.x;
    const int NT = 1024;
    const int wid = t >> 6, lane = t & 63;   // 16 waves
    __shared__ __align__(16) int   cnt[HB1];
    __shared__ __align__(16) float sm[HB1];
    __shared__ int   wc[16];
    __shared__ float ws[16];
    __shared__ int s_strad, s_krem;
    __shared__ float s_above;
    __shared__ int s_last;
    __shared__ float wsum[16], wsA[16], wsB[16];

    const int k = min(3 * num_pos[b], N - 1);
    const float* lcb = lc + (size_t)b * N;
    float total = 0.f;

    if (k > 0) {
        // ---- Level 1: bits [30:19] (4096 buckets), thread owns 4 ----
        ((int4*)cnt)[t] = make_int4(0, 0, 0, 0);
        ((float4*)sm)[t] = make_float4(0.f, 0.f, 0.f, 0.f);
        __syncthreads();
        const int n4 = N >> 2;
        const float4* lcb4 = (const float4*)lcb;
        for (int i = t; i < n4; i += NT) {
            float4 v = lcb4[i];
            { unsigned u = __float_as_uint(v.x) >> 19; atomicAdd(&cnt[u], 1); atomicAdd(&sm[u], v.x); }
            { unsigned u = __float_as_uint(v.y) >> 19; atomicAdd(&cnt[u], 1); atomicAdd(&sm[u], v.y); }
            { unsigned u = __float_as_uint(v.z) >> 19; atomicAdd(&cnt[u], 1); atomicAdd(&sm[u], v.z); }
            { unsigned u = __float_as_uint(v.w) >> 19; atomicAdd(&cnt[u], 1); atomicAdd(&sm[u], v.w); }
        }
        for (int i = (n4 << 2) + t; i < N; i += NT) {
            float v = lcb[i];
            unsigned u = __float_as_uint(v) >> 19;
            atomicAdd(&cnt[u], 1); atomicAdd(&sm[u], v);
        }
        __syncthreads();
        {
            int4  cv = ((const int4*)cnt)[t];
            float4 sv = ((const float4*)sm)[t];
            int   ci = cv.x + cv.y + cv.z + cv.w;
            float si = sv.x + sv.y + sv.z + sv.w;
            wave_sufscan(ci, si, lane);
            if (lane == 0) { wc[wid] = ci; ws[wid] = si; }
            __syncthreads();
            int cab = 0; float sab = 0.f;
            for (int w = wid + 1; w < 16; w++) { cab += wc[w]; sab += ws[w]; }
            int   i0c = ci + cab;          float f0 = si + sab;
            int   i1c = i0c - cv.x;        float f1 = f0 - sv.x;
            int   i2c = i1c - cv.y;        float f2 = f1 - sv.y;
            int   i3c = i2c - cv.z;        float f3 = f2 - sv.z;
            int   i4c = i3c - cv.w;
            if (i1c < k && k <= i0c) { s_strad = 4 * t + 0; s_krem = k - i1c; s_above = f1; }
            if (i2c < k && k <= i1c) { s_strad = 4 * t + 1; s_krem = k - i2c; s_above = f2; }
            if (i3c < k && k <= i2c) { s_strad = 4 * t + 2; s_krem = k - i3c; s_above = f3; }
            if (i4c < k && k <= i3c) { s_strad = 4 * t + 3; s_krem = k - i4c; s_above = f3 - sv.w; }
        }
        __syncthreads();
        const int s1 = s_strad, k2 = s_krem;
        total += s_above;

        // ---- Level 2: bits [18:8] (2048 buckets) within L1 bucket s1, thread owns 2 ----
        __syncthreads();
        ((int2*)cnt)[t] = make_int2(0, 0);
        ((float2*)sm)[t] = make_float2(0.f, 0.f);
        __syncthreads();
        for (int i = t; i < N; i += NT) {
            float v = lcb[i];
            unsigned u = __float_as_uint(v);
            if ((int)(u >> 19) == s1) {
                int q = (int)((u >> 8) & 0x7FF);
                atomicAdd(&cnt[q], 1); atomicAdd(&sm[q], v);
            }
        }
        __syncthreads();
        {
            int2  cv = ((const int2*)cnt)[t];
            float2 sv = ((const float2*)sm)[t];
            int   ci = cv.x + cv.y;
            float si = sv.x + sv.y;
            wave_sufscan(ci, si, lane);
            if (lane == 0) { wc[wid] = ci; ws[wid] = si; }
            __syncthreads();
            int cab = 0; float sab = 0.f;
            for (int w = wid + 1; w < 16; w++) { cab += wc[w]; sab += ws[w]; }
            int   i0c = ci + cab;       float f0 = si + sab;
            int   i1c = i0c - cv.x;     float f1 = f0 - sv.x;
            int   i2c = i1c - cv.y;
            if (i1c < k2 && k2 <= i0c) { s_strad = 2 * t + 0; s_krem = k2 - i1c; s_above = f1; }
            if (i2c < k2 && k2 <= i1c) { s_strad = 2 * t + 1; s_krem = k2 - i2c; s_above = f1 - sv.y; }
        }
        __syncthreads();
        const int s2 = s_strad, krem = s_krem;
        total += s_above;
        float tval = __uint_as_float((((unsigned)s1) << 19) | (((unsigned)s2) << 8));
        total += (float)krem * tval;
    }

    // contribute + last-block finalize
    if (t == 0) {
        if (k > 0) atomicAdd(&acc[1], total);
        __threadfence();
        unsigned old = atomicAdd(done_ctr, 1u);
        s_last = (old == (unsigned)gridDim.x - 1u) ? 1 : 0;
    }
    __syncthreads();
    if (s_last) {
        __threadfence();
        float vn = 0.f, va = 0.f, vb = 0.f;
        for (int q = t; q < B; q += NT) {
            vn += (float)num_pos[q];
            va += accB[q * 2 + 0];
            vb += accB[q * 2 + 1];
        }
#pragma unroll
        for (int off = 32; off >= 1; off >>= 1) {
            vn += __shfl_down(vn, off, 64);
            va += __shfl_down(va, off, 64);
            vb += __shfl_down(vb, off, 64);
        }
        if (lane == 0) { wsum[wid] = vn; wsA[wid] = va; wsB[wid] = vb; }
        __syncthreads();
        if (t == 0) {
            float n = 0.f, a = 0.f, bsum = 0.f;
#pragma unroll
            for (int w = 0; w < 16; w++) { n += wsum[w]; a += wsA[w]; bsum += wsB[w]; }
            float l2 = atomicAdd(&acc[1], 0.0f);
            out[0] = a / n;
            out[1] = (bsum + l2) / n;
        }
    }
}

extern "C" void kernel_launch(void* const* d_in, const int* in_sizes, int n_in,
                              void* d_out, int out_size, void* d_ws, size_t ws_size,
                              hipStream_t stream)
{
    const float* loc     = (const float*)d_in[0];
    const float* conf    = (const float*)d_in[1];
    const float* targets = (const float*)d_in[2];
    const float* priors  = (const float*)d_in[3];
    float* out = (float*)d_out;

    const int N = in_sizes[3] / 4;
    const int BN = in_sizes[0] / 4;
    const int B = BN / N;
    const int NOBJ = in_sizes[2] / (B * 5);
    const int SLICES = 8;
    const int CHUNK = (N + SLICES - 1) / SLICES;
    const int TPB = (N + 255) / 256;     // 256-row tiles per batch
    const int BPB = 6;                   // blocks per batch -> 768 blocks = 3/CU

    // workspace layout
    char* w = (char*)d_ws;
    float*    lc_ws   = (float*)w;                         size_t off = (size_t)BN * 4;
    float*    bpi_val = (float*)(w + off);                 off += (size_t)B * SLICES * 16 * 4;
    int*      bpi_idx = (int*)(w + off);                   off += (size_t)B * SLICES * 16 * 4;
    int*      num_pos = (int*)(w + off);                   off += (size_t)B * 4;
    float*    accB    = (float*)(w + off);                 off += (size_t)B * 2 * 4;
    float*    acc     = (float*)(w + off);                 off += 16;
    unsigned* done    = (unsigned*)(w + off);              off += 16;

    dim3 gA(SLICES, B);
    kA_best_prior<<<gA, 256, 0, stream>>>(targets, priors, bpi_val, bpi_idx,
                                          num_pos, accB, acc, done, N, NOBJ, SLICES, CHUNK, B);

    kB_main<<<B * BPB, 256, 0, stream>>>(loc, conf, targets, priors, bpi_val, bpi_idx,
                                         lc_ws, num_pos, accB, N, NOBJ, SLICES, TPB, BPB);

    kC_topk<<<B, 1024, 0, stream>>>(lc_ws, num_pos, accB, acc, done, out, N, B);
}